// Round 1
// baseline (182.768 us; speedup 1.0000x reference)
//
#include <hip/hip_runtime.h>
#include <stdint.h>

// Soft-logic FP32 adder: faithful integer emulation of the reference gate
// circuit. Inputs are rows of 32 floats in {0.0,1.0}; packing bit j at
// position (31-j) reproduces the IEEE-754 bit layout (sign@31, exp 30..23
// MSB-first, mantissa 22..0 MSB-first).
//
// Circuit quirks faithfully reproduced (these differ from hardware fadd):
//  - exp_diff >= 24  -> return the larger-magnitude ORIGINAL input verbatim
//  - exponent==0 treated as denormal (e_eff=1, hidden=0)
//  - underflow (lzc >= e_max) -> exponent 0, rounding suppressed
//  - subtraction with sticky -> mantissa-1 correction (need_sub_one)
//  - computed exponent == 0xFF -> mantissa forced to 0 (inf clamp)
//  - exact cancellation (diff sign, equal magnitude) -> +0
__device__ __forceinline__ uint32_t fp32_add_circuit(uint32_t a, uint32_t b) {
    const uint32_t s_a = a >> 31, s_b = b >> 31;
    const uint32_t e_a = (a >> 23) & 0xFFu, e_b = (b >> 23) & 0xFFu;
    const uint32_t hid_a = (e_a != 0u) ? 1u : 0u;
    const uint32_t hid_b = (e_b != 0u) ? 1u : 0u;
    const uint32_t e_a_eff = hid_a ? e_a : 1u;          // _MUX(e_a_is_zero, 1, e_a)
    const uint32_t e_b_eff = hid_b ? e_b : 1u;
    const uint32_t mant_a = (hid_a << 23) | (a & 0x7FFFFFu);   // 24-bit [hidden|m]
    const uint32_t mant_b = (hid_b << 23) | (b & 0x7FFFFFu);

    const bool a_abs_eq_b = (e_a_eff == e_b_eff) && (mant_a == mant_b);
    const bool a_ge_b = (e_a_eff > e_b_eff) ||
                        ((e_a_eff == e_b_eff) && (mant_a >= mant_b));

    // 8-bit |exp diff|; big-diff bypass: high_any(diff>=32) OR bits4&3 -> diff>=24
    const uint32_t exp_diff = a_ge_b ? (e_a_eff - e_b_eff) : (e_b_eff - e_a_eff);
    const bool is_big_diff = exp_diff >= 24u;
    const uint32_t sh = exp_diff & 31u;                 // shift_amt = exp_diff[3:8]

    const uint32_t e_max = a_ge_b ? e_a_eff : e_b_eff;
    const uint32_t m_large     = (a_ge_b ? mant_a : mant_b) << 4;  // 28-bit
    const uint32_t m_small_uns = (a_ge_b ? mant_b : mant_a) << 4;
    const uint32_t m_small = m_small_uns >> sh;         // sh <= 31, well-defined
    const bool shift_sticky = (m_small_uns & ((1u << sh) - 1u)) != 0u;

    const bool is_diff_sign = (s_a != s_b);
    const bool exact_cancel = is_diff_sign && a_abs_eq_b;
    const uint32_t s_large = a_ge_b ? s_a : s_b;

    const uint32_t sum = m_large + m_small;             // up to 29 bits
    const uint32_t sum_carry = sum >> 28;
    const uint32_t diff0 = m_large - m_small;           // >= 0 by construction
    // need_sub_one = is_diff_sign && shift_sticky  (diff0>0 whenever sticky set)
    const uint32_t diff1 = (is_diff_sign && shift_sticky) ? (diff0 - 1u) : diff0;

    const uint32_t mant_res = (is_diff_sign ? diff1 : sum) & 0x0FFFFFFFu; // 28-bit
    const uint32_t carry = is_diff_sign ? 0u : sum_carry;                 // result_carry

    // _lzd28: leading zeros of 28-bit value, 28 if zero
    const uint32_t lzc = mant_res ? ((uint32_t)__clz((int)mant_res) - 4u) : 28u;
    const bool is_underflow = (lzc >= e_max);
    const uint32_t norm = (mant_res << lzc) & 0x0FFFFFFFu;  // _bsl, 28-bit window

    const uint32_t e_normal = is_underflow ? 0u : ((e_max - lzc) & 0xFFu);
    const uint32_t final_e_pre = carry ? ((e_max + 1u) & 0xFFu) : e_normal;

    // overflow path: take bits 27..5 / round bit4 / sticky bits3..0
    // norm path:     take bits 26..4 / round bit3 / sticky bits2..0
    const uint32_t m_pre     = carry ? ((mant_res >> 5) & 0x7FFFFFu)
                                     : ((norm >> 4) & 0x7FFFFFu);
    const uint32_t round_pre = carry ? ((mant_res >> 4) & 1u)
                                     : ((norm >> 3) & 1u);
    const bool sticky_raw    = carry ? ((mant_res & 0xFu) != 0u)
                                     : ((norm & 0x7u) != 0u);
    const bool sticky_pre = sticky_raw || ((!is_diff_sign) && shift_sticky);

    const uint32_t m_selected = is_underflow ? ((mant_res >> 5) & 0x7FFFFFu) : m_pre;
    const bool do_round = (round_pre != 0u) && (sticky_pre || (m_selected & 1u))
                          && !is_underflow;
    const uint32_t m24 = m_selected + (do_round ? 1u : 0u);
    const uint32_t round_carry = m24 >> 23;
    const uint32_t m_final = round_carry ? 0u : (m24 & 0x7FFFFFu);
    const uint32_t computed_e = (final_e_pre + round_carry) & 0xFFu;

    // exact-cancel override, then all-ones-exponent override (inf clamp)
    const uint32_t cs = exact_cancel ? 0u : s_large;
    const uint32_t ce = exact_cancel ? 0u : computed_e;
    const uint32_t cm = exact_cancel ? 0u : m_final;
    const bool e_all_one = (computed_e == 0xFFu);
    const uint32_t final_s = e_all_one ? s_large : cs;
    const uint32_t final_e = e_all_one ? 0xFFu : ce;
    const uint32_t final_m = e_all_one ? 0u : cm;

    const uint32_t normal_result = (final_s << 31) | (final_e << 23) | final_m;
    return is_big_diff ? (a_ge_b ? a : b) : normal_result;
}

__global__ __launch_bounds__(256)
void SpikeFP32Adder_kernel(const uint4* __restrict__ A,
                           const uint4* __restrict__ B,
                           uint4* __restrict__ O, int nrows)
{
    const int r = blockIdx.x * 256 + threadIdx.x;
    if (r >= nrows) return;
    const uint4* pa = A + (size_t)r * 8;   // 32 floats = 8 uint4 per row
    const uint4* pb = B + (size_t)r * 8;

    // pack: element j -> bit (31-j). Values are exactly 0x0 or 0x3F800000,
    // so (w>>23)&1 extracts the boolean.
    uint32_t ua = 0u, ub = 0u;
#pragma unroll
    for (int k = 0; k < 8; ++k) {
        const uint4 va = pa[k], vb = pb[k];
        ua = (ua << 4) | (((va.x >> 23) & 1u) << 3) | (((va.y >> 23) & 1u) << 2)
                       | (((va.z >> 23) & 1u) << 1) | ((va.w >> 23) & 1u);
        ub = (ub << 4) | (((vb.x >> 23) & 1u) << 3) | (((vb.y >> 23) & 1u) << 2)
                       | (((vb.z >> 23) & 1u) << 1) | ((vb.w >> 23) & 1u);
    }

    const uint32_t res = fp32_add_circuit(ua, ub);

    uint4* po = O + (size_t)r * 8;
#pragma unroll
    for (int k = 0; k < 8; ++k) {
        uint4 vo;
        vo.x = ((res >> (31 - 4 * k)) & 1u) * 0x3F800000u;
        vo.y = ((res >> (30 - 4 * k)) & 1u) * 0x3F800000u;
        vo.z = ((res >> (29 - 4 * k)) & 1u) * 0x3F800000u;
        vo.w = ((res >> (28 - 4 * k)) & 1u) * 0x3F800000u;
        po[k] = vo;
    }
}

extern "C" void kernel_launch(void* const* d_in, const int* in_sizes, int n_in,
                              void* d_out, int out_size, void* d_ws, size_t ws_size,
                              hipStream_t stream) {
    const uint4* A = (const uint4*)d_in[0];
    const uint4* B = (const uint4*)d_in[1];
    uint4* O = (uint4*)d_out;
    const int nrows = in_sizes[0] / 32;          // 524288
    const int block = 256;
    const int grid = (nrows + block - 1) / block; // 2048 blocks
    SpikeFP32Adder_kernel<<<grid, block, 0, stream>>>(A, B, O, nrows);
}

// Round 2
// 165.134 us; speedup vs baseline: 1.1068x; 1.1068x over previous
//
#include <hip/hip_runtime.h>
#include <stdint.h>

// Soft-logic FP32 adder, round 2: lane-major coalesced layout.
//
// Layout: 8 consecutive lanes own one row of 32 floats. Lane L = 8r+m loads
// float4 covering row-r elements 4m..4m+3 (16 B/lane, perfectly coalesced —
// the 6.3 TB/s copy pattern). Each lane builds a 4-bit nibble at its bit
// position; a 3-step __shfl_xor OR-butterfly (d=1,2,4) assembles the full
// packed 32-bit word in every lane of the group. All 8 lanes redundantly run
// the integer circuit (VALU is ~10x under-utilized), then each lane unpacks
// and stores its own float4 — stores coalesced too. No LDS.
//
// Bit convention: element j of a row -> bit (31-j) of the packed word, which
// is exactly the IEEE-754 layout (sign@31, exp MSB-first, mantissa MSB-first).

__device__ __forceinline__ uint32_t fp32_add_circuit(uint32_t a, uint32_t b) {
    const uint32_t s_a = a >> 31, s_b = b >> 31;
    const uint32_t e_a = (a >> 23) & 0xFFu, e_b = (b >> 23) & 0xFFu;
    const uint32_t hid_a = (e_a != 0u) ? 1u : 0u;
    const uint32_t hid_b = (e_b != 0u) ? 1u : 0u;
    const uint32_t e_a_eff = hid_a ? e_a : 1u;          // _MUX(e_a_is_zero, 1, e_a)
    const uint32_t e_b_eff = hid_b ? e_b : 1u;
    const uint32_t mant_a = (hid_a << 23) | (a & 0x7FFFFFu);   // 24-bit [hidden|m]
    const uint32_t mant_b = (hid_b << 23) | (b & 0x7FFFFFu);

    const bool a_abs_eq_b = (e_a_eff == e_b_eff) && (mant_a == mant_b);
    const bool a_ge_b = (e_a_eff > e_b_eff) ||
                        ((e_a_eff == e_b_eff) && (mant_a >= mant_b));

    // 8-bit |exp diff|; big-diff bypass (>=24) returns larger input verbatim
    const uint32_t exp_diff = a_ge_b ? (e_a_eff - e_b_eff) : (e_b_eff - e_a_eff);
    const bool is_big_diff = exp_diff >= 24u;
    const uint32_t sh = exp_diff & 31u;                 // shift_amt = exp_diff[3:8]

    const uint32_t e_max = a_ge_b ? e_a_eff : e_b_eff;
    const uint32_t m_large     = (a_ge_b ? mant_a : mant_b) << 4;  // 28-bit
    const uint32_t m_small_uns = (a_ge_b ? mant_b : mant_a) << 4;
    const uint32_t m_small = m_small_uns >> sh;         // sh <= 31, well-defined
    const bool shift_sticky = (m_small_uns & ((1u << sh) - 1u)) != 0u;

    const bool is_diff_sign = (s_a != s_b);
    const bool exact_cancel = is_diff_sign && a_abs_eq_b;
    const uint32_t s_large = a_ge_b ? s_a : s_b;

    const uint32_t sum = m_large + m_small;             // up to 29 bits
    const uint32_t sum_carry = sum >> 28;
    const uint32_t diff0 = m_large - m_small;           // >= 0 by construction
    const uint32_t diff1 = (is_diff_sign && shift_sticky) ? (diff0 - 1u) : diff0;

    const uint32_t mant_res = (is_diff_sign ? diff1 : sum) & 0x0FFFFFFFu; // 28-bit
    const uint32_t carry = is_diff_sign ? 0u : sum_carry;                 // result_carry

    // _lzd28: leading zeros of 28-bit value, 28 if zero
    const uint32_t lzc = mant_res ? ((uint32_t)__clz((int)mant_res) - 4u) : 28u;
    const bool is_underflow = (lzc >= e_max);
    const uint32_t norm = (mant_res << lzc) & 0x0FFFFFFFu;  // _bsl, 28-bit window

    const uint32_t e_normal = is_underflow ? 0u : ((e_max - lzc) & 0xFFu);
    const uint32_t final_e_pre = carry ? ((e_max + 1u) & 0xFFu) : e_normal;

    const uint32_t m_pre     = carry ? ((mant_res >> 5) & 0x7FFFFFu)
                                     : ((norm >> 4) & 0x7FFFFFu);
    const uint32_t round_pre = carry ? ((mant_res >> 4) & 1u)
                                     : ((norm >> 3) & 1u);
    const bool sticky_raw    = carry ? ((mant_res & 0xFu) != 0u)
                                     : ((norm & 0x7u) != 0u);
    const bool sticky_pre = sticky_raw || ((!is_diff_sign) && shift_sticky);

    const uint32_t m_selected = is_underflow ? ((mant_res >> 5) & 0x7FFFFFu) : m_pre;
    const bool do_round = (round_pre != 0u) && (sticky_pre || (m_selected & 1u))
                          && !is_underflow;
    const uint32_t m24 = m_selected + (do_round ? 1u : 0u);
    const uint32_t round_carry = m24 >> 23;
    const uint32_t m_final = round_carry ? 0u : (m24 & 0x7FFFFFu);
    const uint32_t computed_e = (final_e_pre + round_carry) & 0xFFu;

    // exact-cancel override, then all-ones-exponent override (inf clamp)
    const uint32_t cs = exact_cancel ? 0u : s_large;
    const uint32_t ce = exact_cancel ? 0u : computed_e;
    const uint32_t cm = exact_cancel ? 0u : m_final;
    const bool e_all_one = (computed_e == 0xFFu);
    const uint32_t final_s = e_all_one ? s_large : cs;
    const uint32_t final_e = e_all_one ? 0xFFu : ce;
    const uint32_t final_m = e_all_one ? 0u : cm;

    const uint32_t normal_result = (final_s << 31) | (final_e << 23) | final_m;
    return is_big_diff ? (a_ge_b ? a : b) : normal_result;
}

__global__ __launch_bounds__(256)
void SpikeFP32Adder_kernel(const uint4* __restrict__ A,
                           const uint4* __restrict__ B,
                           uint4* __restrict__ O, int nvec4)
{
    const int gid = blockIdx.x * 256 + threadIdx.x;
    if (gid >= nvec4) return;
    const int m = threadIdx.x & 7;          // position within the 8-lane row group
    const int pos = 28 - 4 * m;             // nibble's bit offset in packed word

    const uint4 va = A[gid];                // row-r elements 4m..4m+3
    const uint4 vb = B[gid];

    // values are exactly 0x0 or 0x3F800000; (w>>23)&1 extracts the boolean.
    // element 4m+c -> packed bit 31-4m-c: x at pos+3, y pos+2, z pos+1, w pos.
    uint32_t pa = ((((va.x >> 23) & 1u) << 3) | (((va.y >> 23) & 1u) << 2) |
                   (((va.z >> 23) & 1u) << 1) |  ((va.w >> 23) & 1u)) << pos;
    uint32_t pb = ((((vb.x >> 23) & 1u) << 3) | (((vb.y >> 23) & 1u) << 2) |
                   (((vb.z >> 23) & 1u) << 1) |  ((vb.w >> 23) & 1u)) << pos;

    // OR-butterfly across the 8-lane group: after d=1,2,4 every lane holds the
    // group's full packed word (each lane contributed a distinct nibble).
    pa |= (uint32_t)__shfl_xor((int)pa, 1, 64);
    pb |= (uint32_t)__shfl_xor((int)pb, 1, 64);
    pa |= (uint32_t)__shfl_xor((int)pa, 2, 64);
    pb |= (uint32_t)__shfl_xor((int)pb, 2, 64);
    pa |= (uint32_t)__shfl_xor((int)pa, 4, 64);
    pb |= (uint32_t)__shfl_xor((int)pb, 4, 64);

    const uint32_t res = fp32_add_circuit(pa, pb);

    uint4 vo;
    vo.x = ((res >> (pos + 3)) & 1u) * 0x3F800000u;
    vo.y = ((res >> (pos + 2)) & 1u) * 0x3F800000u;
    vo.z = ((res >> (pos + 1)) & 1u) * 0x3F800000u;
    vo.w = ((res >>  pos     ) & 1u) * 0x3F800000u;
    O[gid] = vo;
}

extern "C" void kernel_launch(void* const* d_in, const int* in_sizes, int n_in,
                              void* d_out, int out_size, void* d_ws, size_t ws_size,
                              hipStream_t stream) {
    const uint4* A = (const uint4*)d_in[0];
    const uint4* B = (const uint4*)d_in[1];
    uint4* O = (uint4*)d_out;
    const int nvec4 = in_sizes[0] / 4;            // 4,194,304 float4 groups
    const int block = 256;
    const int grid = (nvec4 + block - 1) / block; // 16384 blocks
    SpikeFP32Adder_kernel<<<grid, block, 0, stream>>>(A, B, O, nvec4);
}